// Round 18
// baseline (545.443 us; speedup 1.0000x reference)
//
#include <hip/hip_runtime.h>
#include <hip/hip_fp16.h>

#define HDIM  50
#define G3    150
#define TSEQ  512
#define BATCH 2048
#define NBC   16      // batch cols per block (all real)
#define NLAY  4

typedef _Float16 f16x8 __attribute__((ext_vector_type(8)));
typedef float    f32x4 __attribute__((ext_vector_type(4)));

#define MFMA(a,b,c) __builtin_amdgcn_mfma_f32_16x16x32_f16((a),(b),(c),0,0,0)

static __device__ inline unsigned pk2(float a, float b) {
    return __builtin_bit_cast(unsigned, __builtin_amdgcn_cvt_pkrtz(a, b));
}
static __device__ inline float rcpf(float x) { return __builtin_amdgcn_rcpf(x); }

#if __has_builtin(__builtin_amdgcn_exp2f)
static __device__ inline float ex2(float x) { return __builtin_amdgcn_exp2f(x); }
#else
static __device__ inline float ex2(float x) {
    float r; asm volatile("v_exp_f32 %0, %1" : "=v"(r) : "v"(x)); return r;
}
#endif

// Weight pre-scaling folded at fragment load:
//   r,z columns * -log2(e):  sigmoid(g) = rcp(1 + exp2(acc))
//   n  columns * +2*log2(e): tanh(v)    = 1 - 2*rcp(exp2(acc) + 1)
#define SCL_RZ (-1.44269504f)
#define SCL_N  ( 2.88539008f)

// 16 waves/block: wave (lay, wt) owns M-tile rows [16*wt, 16*wt+16) of all 3
// gate blocks of layer `lay`. 4 waves/SIMD (VGPR capped at 128) so MFMA /
// trans / DS latencies overlap across waves. Blocks i and i+128 duplicate
// batches (only i<128 writes). One barrier/step, parity double-buffered LDS.
__global__ __launch_bounds__(1024, 4)
void gru_16w(const float* __restrict__ xin,
             const float* __restrict__ Wih0, const float* __restrict__ Whh0,
             const float* __restrict__ bih0, const float* __restrict__ bhh0,
             const float* __restrict__ WihL, const float* __restrict__ WhhL,
             const float* __restrict__ bihL, const float* __restrict__ bhhL,
             const float* __restrict__ fcw,  const float* __restrict__ fcb,
             float* __restrict__ out)
{
    const int tid  = threadIdx.x;
    const int wid  = tid >> 6;
    const int lay  = wid >> 2;         // 0..3
    const int wt   = wid & 3;          // M-tile: rows [16*wt, 16*wt+16)
    const int lane = tid & 63;
    const int lb   = lane & 15;        // batch col
    const int lg   = lane >> 4;        // k-octet (B) / C row group
    const int b0   = (blockIdx.x & 127) * NBC;
    const bool wr  = (blockIdx.x < 128);

    __shared__ __align__(16) _Float16 hsl[NLAY][2][16][72];  // k=50 = const 1.0
    __shared__ float x_row[NBC][516];

    const float* Wih = (lay==0) ? Wih0 : WihL + (size_t)(lay-1)*G3*HDIM;
    const float* Whh = (lay==0) ? Whh0 : WhhL + (size_t)(lay-1)*G3*HDIM;
    const float* bih = (lay==0) ? bih0 : bihL + (lay-1)*G3;
    const float* bhh = (lay==0) ? bhh0 : bhhL + (lay-1)*G3;

    // ---- A fragments [gate][kt]; biases folded at k==50; scales folded ----
    const int  ur = 16*wt + lb;            // absolute gate-row 0..63
    const bool rv = ur < HDIM;
    f16x8 a_hh[3][2], a_ih[3][2];
#pragma unroll
    for (int g = 0; g < 3; ++g) {
        const int  gr  = 50*g + (rv ? ur : 0);
        const float scl = (g < 2) ? SCL_RZ : SCL_N;
#pragma unroll
        for (int kt = 0; kt < 2; ++kt) {
            f16x8 fh, fi;
#pragma unroll
            for (int j = 0; j < 8; ++j) {
                const int k = 32*kt + 8*lg + j;
                float vh = 0.f, vi = 0.f;
                if (rv) {
                    if (k < HDIM)       vh = Whh[gr*HDIM + k];
                    else if (k == HDIM) vh = bhh[gr];
                    if (lay == 0) {
                        if (kt == 0 && k == 0)      vi = Wih[gr];
                        else if (kt == 0 && k == 1) vi = bih[gr];
                    } else {
                        if (k < HDIM)       vi = Wih[gr*HDIM + k];
                        else if (k == HDIM) vi = bih[gr];
                    }
                }
                fh[j] = (_Float16)(vh * scl); fi[j] = (_Float16)(vi * scl);
            }
            a_hh[g][kt] = fh; a_ih[g][kt] = fi;
        }
    }

    // ---- stage x; init h_lds (h=0, bias slot 50 = 1.0, both parities) ----
    for (int k = tid; k < NBC*TSEQ; k += 1024)
        x_row[k >> 9][k & 511] = xin[(size_t)(b0 + (k >> 9))*TSEQ + (k & 511)];
    for (int k = tid; k < NLAY*2*16*72; k += 1024)
        ((_Float16*)hsl)[k] = (_Float16)(((k % 72) == HDIM) ? 1.f : 0.f);

    float hold[4];                     // persistent h for this wave's 4 rows/lane
#pragma unroll
    for (int i = 0; i < 4; ++i) hold[i] = 0.f;
    __syncthreads();

    f16x8 bh0 = *(const f16x8*)&hsl[lay][1][lb][8*lg];
    f16x8 bh1 = *(const f16x8*)&hsl[lay][1][lb][32 + 8*lg];
    f16x8 bx0{}, bx1{};
    if (lay == 0) {
#pragma unroll
        for (int j = 0; j < 8; ++j) bx0[j] = (_Float16)0.f;
        if (lg == 0) { bx0[0] = (_Float16)x_row[lb][0]; bx0[1] = (_Float16)1.f; }
    } else {
        bx0 = *(const f16x8*)&hsl[lay-1][1][lb][8*lg];
        bx1 = *(const f16x8*)&hsl[lay-1][1][lb][32 + 8*lg];
    }
    const f32x4 Z4 = {0.f, 0.f, 0.f, 0.f};

    // per-lane row validity within this wave's tile: row = 16*wt + 4*lg + i
    // wt<3: all valid; wt==3: valid iff lg==0 && i<2 (rows 48,49)
    const bool t3 = (wt == 3);

    for (int s = 0; s < TSEQ + NLAY - 1; ++s) {
        const int t = s - lay;
        if (t >= 0 && t < TSEQ) {
            f32x4 acc[3], accx;
#pragma unroll
            for (int g = 0; g < 3; ++g) acc[g] = MFMA(a_hh[g][0], bh0, Z4);
#pragma unroll
            for (int g = 0; g < 3; ++g) acc[g] = MFMA(a_hh[g][1], bh1, acc[g]);
#pragma unroll
            for (int g = 0; g < 2; ++g) acc[g] = MFMA(a_ih[g][0], bx0, acc[g]);
            accx = MFMA(a_ih[2][0], bx0, Z4);
            if (lay != 0) {
#pragma unroll
                for (int g = 0; g < 2; ++g) acc[g] = MFMA(a_ih[g][1], bx1, acc[g]);
                accx = MFMA(a_ih[2][1], bx1, accx);
            }

            // r,z sigmoids: rcp(1 + exp2(acc)) (weights pre-scaled)
#pragma unroll
            for (int g = 0; g < 2; ++g)
#pragma unroll
                for (int i = 0; i < 4; ++i) {
                    if (t3 && i >= 2) continue;               // rows >= 50
                    acc[g][i] = rcpf(1.f + ex2(acc[g][i]));
                }

            // n gate + h update
            float hp[4];
#pragma unroll
            for (int i = 0; i < 4; ++i) {
                if (t3 && i >= 2) { hp[i] = 0.f; continue; }
                const float r  = acc[0][i];
                const float z  = acc[1][i];
                const float vp = accx[i] + r * acc[2][i];     // pre-scaled
                const float n  = 1.f - 2.f*rcpf(ex2(vp) + 1.f);
                const float h  = fmaf(z, hold[i] - n, n);     // (1-z)n + zh
                hold[i] = h;
                hp[i] = h;
            }

            // publish this wave's tile rows [16wt+4lg, +4) of h(t)
            {
                _Float16* hrow = &hsl[lay][s & 1][lb][0];
                if (!t3) {
                    uint2 q; q.x = pk2(hp[0], hp[1]);
                             q.y = pk2(hp[2], hp[3]);
                    *(uint2*)&hrow[16*wt + 4*lg] = q;
                } else if (lg == 0) {   // rows 48,49 only; never touch k=50 bias
                    *(unsigned*)&hrow[48] = pk2(hp[0], hp[1]);
                }
            }
        }
        __syncthreads();   // h(t) fully assembled in buf[s&1]

        const int pb = s & 1;
        bh0 = *(const f16x8*)&hsl[lay][pb][lb][8*lg];
        bh1 = *(const f16x8*)&hsl[lay][pb][lb][32 + 8*lg];
        if (lay == 0) {
            const int tt = (s+1 < TSEQ) ? s+1 : TSEQ-1;
            if (lg == 0) bx0[0] = (_Float16)x_row[lb][tt];
        } else {
            bx0 = *(const f16x8*)&hsl[lay-1][pb][lb][8*lg];
            bx1 = *(const f16x8*)&hsl[lay-1][pb][lb][32 + 8*lg];
        }
    }

    // ---- fused FC + sigmoid on layer-3 final h (s=514 -> parity 0) ----
    if (wr && tid < NBC) {
        float sacc = fcb[0];
#pragma unroll
        for (int j = 0; j < HDIM; ++j)
            sacc = fmaf((float)hsl[NLAY-1][0][tid][j], fcw[j], sacc);
        out[b0 + tid] = rcpf(1.f + __expf(-sacc));
    }
}

extern "C" void kernel_launch(void* const* d_in, const int* in_sizes, int n_in,
                              void* d_out, int out_size, void* d_ws, size_t ws_size,
                              hipStream_t stream) {
    const float* x     = (const float*)d_in[0];
    const float* W_ih0 = (const float*)d_in[1];
    const float* W_hh0 = (const float*)d_in[2];
    const float* b_ih0 = (const float*)d_in[3];
    const float* b_hh0 = (const float*)d_in[4];
    const float* W_ih  = (const float*)d_in[5];
    const float* W_hh  = (const float*)d_in[6];
    const float* b_ih  = (const float*)d_in[7];
    const float* b_hh  = (const float*)d_in[8];
    const float* fc_w  = (const float*)d_in[9];
    const float* fc_b  = (const float*)d_in[10];
    float* out = (float*)d_out;

    dim3 grid(256), block(1024);   // blocks i and i+128 duplicate; i<128 writes
    gru_16w<<<grid, block, 0, stream>>>(
        x, W_ih0, W_hh0, b_ih0, b_hh0,
        W_ih, W_hh, b_ih, b_hh, fc_w, fc_b, out);
}

// Round 19
// 513.662 us; speedup vs baseline: 1.0619x; 1.0619x over previous
//
#include <hip/hip_runtime.h>
#include <hip/hip_fp16.h>

#define HDIM  50
#define G3    150
#define TSEQ  512
#define NBC   16      // batch cols per block (all real)
#define NLAY  4

typedef _Float16 f16x8 __attribute__((ext_vector_type(8)));
typedef float    f32x4 __attribute__((ext_vector_type(4)));

#define MFMA(a,b,c) __builtin_amdgcn_mfma_f32_16x16x32_f16((a),(b),(c),0,0,0)

static __device__ inline unsigned pk2(float a, float b) {
    return __builtin_bit_cast(unsigned, __builtin_amdgcn_cvt_pkrtz(a, b));
}
static __device__ inline float rcpf(float x) { return __builtin_amdgcn_rcpf(x); }

#if __has_builtin(__builtin_amdgcn_exp2f)
static __device__ inline float ex2(float x) { return __builtin_amdgcn_exp2f(x); }
#else
static __device__ inline float ex2(float x) {
    float r; asm volatile("v_exp_f32 %0, %1" : "=v"(r) : "v"(x)); return r;
}
#endif

// Weight pre-scaling folded at fragment load:
//   r,z columns * -log2(e):  sigmoid(g) = rcp(1 + exp2(acc))
//   n  columns * +2*log2(e): tanh(v)    = 1 - 2*rcp(exp2(acc) + 1)
#define SCL_RZ (-1.44269504f)
#define SCL_N  ( 2.88539008f)

// r17 skeleton (8 waves: wave (lay, wm) owns rows [32wm,32wm+32) of layer
// lay's gates; 2 waves/SIMD) + FRAGMENT-ORDER LDS: h stored exactly in the
// B-fragment register layout -- lane l reads its 16B at l*16, zero bank
// conflicts, static addresses. Writers scatter via the closed-form inverse
// map (2-way pattern = free). s-loop unrolled x2 so parity is compile-time.
__global__ __launch_bounds__(512, 2)
void gru_frag(const float* __restrict__ xin,
              const float* __restrict__ Wih0, const float* __restrict__ Whh0,
              const float* __restrict__ bih0, const float* __restrict__ bhh0,
              const float* __restrict__ WihL, const float* __restrict__ WhhL,
              const float* __restrict__ bihL, const float* __restrict__ bhhL,
              const float* __restrict__ fcw,  const float* __restrict__ fcb,
              float* __restrict__ out)
{
    const int tid  = threadIdx.x;
    const int wid  = tid >> 6;
    const int lay  = wid >> 1;         // 0..3
    const int wm   = wid & 1;          // M-half: rows [32*wm, 32*wm+32)
    const int lane = tid & 63;
    const int lb   = lane & 15;        // batch col
    const int lg   = lane >> 4;        // k-octet (B) / C row group
    const int b0   = (blockIdx.x & 127) * NBC;
    const bool wr  = (blockIdx.x < 128);

    // h in B-fragment order: hf[lay][parity][kt][lane*8 + j] holds
    // h[k = 32*kt + 8*(lane>>4) + j][batch = lane&15].  k=50 = const 1.0.
    __shared__ __align__(16) _Float16 hf[NLAY][2][2][512];
    __shared__ float x_row[NBC][516];

    const float* Wih = (lay==0) ? Wih0 : WihL + (size_t)(lay-1)*G3*HDIM;
    const float* Whh = (lay==0) ? Whh0 : WhhL + (size_t)(lay-1)*G3*HDIM;
    const float* bih = (lay==0) ? bih0 : bihL + (lay-1)*G3;
    const float* bhh = (lay==0) ? bhh0 : bhhL + (lay-1)*G3;

    // ---- A fragments [gate][sub][kt]; biases folded at k==50; scales folded ----
    f16x8 a_hh[3][2][2], a_ih[3][2][2];
#pragma unroll
    for (int g = 0; g < 3; ++g) {
#pragma unroll
        for (int sub = 0; sub < 2; ++sub) {
            const int  ur = (2*wm + sub)*16 + lb;   // absolute row 0..63
            const bool rv = ur < HDIM;
            const int  gr = 50*g + (rv ? ur : 0);
            const float scl = (g < 2) ? SCL_RZ : SCL_N;
#pragma unroll
            for (int kt = 0; kt < 2; ++kt) {
                f16x8 fh, fi;
#pragma unroll
                for (int j = 0; j < 8; ++j) {
                    const int k = 32*kt + 8*lg + j;
                    float vh = 0.f, vi = 0.f;
                    if (rv) {
                        if (k < HDIM)       vh = Whh[gr*HDIM + k];
                        else if (k == HDIM) vh = bhh[gr];
                        if (lay == 0) {
                            if (kt == 0 && k == 0)      vi = Wih[gr];
                            else if (kt == 0 && k == 1) vi = bih[gr];
                        } else {
                            if (k < HDIM)       vi = Wih[gr*HDIM + k];
                            else if (k == HDIM) vi = bih[gr];
                        }
                    }
                    fh[j] = (_Float16)(vh * scl); fi[j] = (_Float16)(vi * scl);
                }
                a_hh[g][sub][kt] = fh; a_ih[g][sub][kt] = fi;
            }
        }
    }

    // ---- stage x; init hf: zeros + bias 1.0 at k=50, both parities ----
    for (int k = tid; k < NBC*TSEQ; k += 512)
        x_row[k >> 9][k & 511] = xin[(size_t)(b0 + (k >> 9))*TSEQ + (k & 511)];
    for (int k = tid; k < NLAY*2*2*512; k += 512) {
        // within one [2][512] lay/parity block: bias lives at w = 770 + 8b
        const int w = k & 1023;
        const bool isb = (w >= 770) && (w <= 890) && (((w - 770) & 7) == 0);
        ((_Float16*)hf)[k] = (_Float16)(isb ? 1.f : 0.f);
    }

    float hold[2][4];                  // persistent h for this wave's rows
#pragma unroll
    for (int sub = 0; sub < 2; ++sub)
#pragma unroll
        for (int i = 0; i < 4; ++i) hold[sub][i] = 0.f;
    __syncthreads();

    const int lane8 = lane * 8;
    // preload from parity 1 ("state of step -1" = init)
    f16x8 bh0 = *(const f16x8*)&hf[lay][1][0][lane8];
    f16x8 bh1 = *(const f16x8*)&hf[lay][1][1][lane8];
    f16x8 bx0{}, bx1{};
    if (lay == 0) {
#pragma unroll
        for (int j = 0; j < 8; ++j) bx0[j] = (_Float16)0.f;
        if (lg == 0) { bx0[0] = (_Float16)x_row[lb][0]; bx0[1] = (_Float16)1.f; }
    } else {
        bx0 = *(const f16x8*)&hf[lay-1][1][0][lane8];
        bx1 = *(const f16x8*)&hf[lay-1][1][1][lane8];
    }
    const f32x4 Z4 = {0.f, 0.f, 0.f, 0.f};

    auto body = [&](int s, int P) {
        const int t = s - lay;
        if (t >= 0 && t < TSEQ) {
            f32x4 acc[3][2], accx[2];
#pragma unroll
            for (int g = 0; g < 3; ++g)
#pragma unroll
                for (int sub = 0; sub < 2; ++sub)
                    acc[g][sub] = MFMA(a_hh[g][sub][0], bh0, Z4);
#pragma unroll
            for (int g = 0; g < 3; ++g)
#pragma unroll
                for (int sub = 0; sub < 2; ++sub)
                    acc[g][sub] = MFMA(a_hh[g][sub][1], bh1, acc[g][sub]);
#pragma unroll
            for (int g = 0; g < 2; ++g)
#pragma unroll
                for (int sub = 0; sub < 2; ++sub)
                    acc[g][sub] = MFMA(a_ih[g][sub][0], bx0, acc[g][sub]);
#pragma unroll
            for (int sub = 0; sub < 2; ++sub)
                accx[sub] = MFMA(a_ih[2][sub][0], bx0, Z4);
            if (lay != 0) {
#pragma unroll
                for (int g = 0; g < 2; ++g)
#pragma unroll
                    for (int sub = 0; sub < 2; ++sub)
                        acc[g][sub] = MFMA(a_ih[g][sub][1], bx1, acc[g][sub]);
#pragma unroll
                for (int sub = 0; sub < 2; ++sub)
                    accx[sub] = MFMA(a_ih[2][sub][1], bx1, accx[sub]);
            }

            // r,z sigmoids: rcp(1 + exp2(acc)) (weights pre-scaled)
#pragma unroll
            for (int g = 0; g < 2; ++g)
#pragma unroll
                for (int sub = 0; sub < 2; ++sub)
#pragma unroll
                    for (int i = 0; i < 4; ++i) {
                        if (wm == 1 && sub == 1 && i >= 2) continue;  // rows >= 50
                        acc[g][sub][i] = rcpf(1.f + ex2(acc[g][sub][i]));
                    }

            // n gate + h update
            float hp[2][4];
#pragma unroll
            for (int sub = 0; sub < 2; ++sub)
#pragma unroll
                for (int i = 0; i < 4; ++i) {
                    if (wm == 1 && sub == 1 && i >= 2) { hp[sub][i] = 0.f; continue; }
                    const float r  = acc[0][sub][i];
                    const float z  = acc[1][sub][i];
                    const float vp = accx[sub][i] + r * acc[2][sub][i];  // pre-scaled
                    const float n  = 1.f - 2.f*rcpf(ex2(vp) + 1.f);
                    const float h  = fmaf(z, hold[sub][i] - n, n);       // (1-z)n + zh
                    hold[sub][i] = h;
                    hp[sub][i] = h;
                }

            // publish into fragment order: rows 16wt+4lg+{0..3} -> lane (lb+16*oct)
#pragma unroll
            for (int sub = 0; sub < 2; ++sub) {
                const int wt   = 2*wm + sub;
                const int kt_w = wt >> 1;
                const int oct  = 2*(wt & 1) + (lg >> 1);
                const int j0   = 4*(lg & 1);
                _Float16* dst = &hf[lay][P][kt_w][(lb + 16*oct)*8 + j0];
                if (wt < 3) {
                    uint2 q; q.x = pk2(hp[sub][0], hp[sub][1]);
                             q.y = pk2(hp[sub][2], hp[sub][3]);
                    *(uint2*)dst = q;
                } else if (lg == 0) {   // rows 48,49 only; k=50 bias untouched
                    *(unsigned*)dst = pk2(hp[1][0], hp[1][1]);
                }
            }
        }
        __syncthreads();   // h(t) fully assembled in parity P

        bh0 = *(const f16x8*)&hf[lay][P][0][lane8];
        bh1 = *(const f16x8*)&hf[lay][P][1][lane8];
        if (lay == 0) {
            const int tt = (s+1 < TSEQ) ? s+1 : TSEQ-1;
            if (lg == 0) bx0[0] = (_Float16)x_row[lb][tt];
        } else {
            bx0 = *(const f16x8*)&hf[lay-1][P][0][lane8];
            bx1 = *(const f16x8*)&hf[lay-1][P][1][lane8];
        }
    };

    // 516 steps, unrolled x2 (parity compile-time); last body idles harmlessly
    for (int s = 0; s < TSEQ + NLAY; s += 2) {
        body(s,     0);
        body(s + 1, 1);
    }

    // ---- fused FC + sigmoid on layer-3 final h (t=511 -> s=514 -> parity 0) ----
    if (wr && tid < NBC) {
        float sacc = fcb[0];
#pragma unroll
        for (int j = 0; j < HDIM; ++j) {
            const int kt = j >> 5, oc = (j & 31) >> 3, jj = j & 7;
            sacc = fmaf((float)hf[NLAY-1][0][kt][(tid + 16*oc)*8 + jj], fcw[j], sacc);
        }
        out[b0 + tid] = rcpf(1.f + __expf(-sacc));
    }
}

extern "C" void kernel_launch(void* const* d_in, const int* in_sizes, int n_in,
                              void* d_out, int out_size, void* d_ws, size_t ws_size,
                              hipStream_t stream) {
    const float* x     = (const float*)d_in[0];
    const float* W_ih0 = (const float*)d_in[1];
    const float* W_hh0 = (const float*)d_in[2];
    const float* b_ih0 = (const float*)d_in[3];
    const float* b_hh0 = (const float*)d_in[4];
    const float* W_ih  = (const float*)d_in[5];
    const float* W_hh  = (const float*)d_in[6];
    const float* b_ih  = (const float*)d_in[7];
    const float* b_hh  = (const float*)d_in[8];
    const float* fc_w  = (const float*)d_in[9];
    const float* fc_b  = (const float*)d_in[10];
    float* out = (float*)d_out;

    dim3 grid(256), block(512);   // blocks i and i+128 duplicate; i<128 writes
    gru_frag<<<grid, block, 0, stream>>>(
        x, W_ih0, W_hh0, b_ih0, b_hh0,
        W_ih, W_hh, b_ih, b_hh, fc_w, fc_b, out);
}

// Round 20
// 497.189 us; speedup vs baseline: 1.0971x; 1.0331x over previous
//
#include <hip/hip_runtime.h>
#include <hip/hip_fp16.h>

#define HDIM  50
#define G3    150
#define TSEQ  512
#define NBC   16      // batch cols per block (all real)
#define NLAY  4

typedef _Float16 f16x8 __attribute__((ext_vector_type(8)));
typedef float    f32x4 __attribute__((ext_vector_type(4)));

#define MFMA(a,b,c) __builtin_amdgcn_mfma_f32_16x16x32_f16((a),(b),(c),0,0,0)

static __device__ inline unsigned pk2(float a, float b) {
    return __builtin_bit_cast(unsigned, __builtin_amdgcn_cvt_pkrtz(a, b));
}
static __device__ inline float rcpf(float x) { return __builtin_amdgcn_rcpf(x); }

#if __has_builtin(__builtin_amdgcn_exp2f)
static __device__ inline float ex2(float x) { return __builtin_amdgcn_exp2f(x); }
#else
static __device__ inline float ex2(float x) {
    float r; asm volatile("v_exp_f32 %0, %1" : "=v"(r) : "v"(x)); return r;
}
#endif

// Weight pre-scaling folded at fragment load:
//   r,z columns * -log2(e):  sigmoid(g) = rcp(1 + exp2(acc))
//   n  columns * +2*log2(e): tanh(v)    = 1 - 2*rcp(exp2(acc) + 1)
#define SCL_RZ (-1.44269504f)
#define SCL_N  ( 2.88539008f)

// 16 waves (wave (lay,wt) owns rows [16wt,16wt+16) of layer lay's 3 gates;
// 4 waves/SIMD) x fragment-order LDS (lane-linear zero-conflict ds_read_b128,
// closed-form scatter on write -- both validated separately in r18/r19).
// One barrier/step, parity double-buffered, s-loop unrolled x2.
__global__ __launch_bounds__(1024, 4)
void gru_16wf(const float* __restrict__ xin,
              const float* __restrict__ Wih0, const float* __restrict__ Whh0,
              const float* __restrict__ bih0, const float* __restrict__ bhh0,
              const float* __restrict__ WihL, const float* __restrict__ WhhL,
              const float* __restrict__ bihL, const float* __restrict__ bhhL,
              const float* __restrict__ fcw,  const float* __restrict__ fcb,
              float* __restrict__ out)
{
    const int tid  = threadIdx.x;
    const int wid  = tid >> 6;
    const int lay  = wid >> 2;         // 0..3
    const int wt   = wid & 3;          // M-tile: rows [16*wt, 16*wt+16)
    const int lane = tid & 63;
    const int lb   = lane & 15;        // batch col
    const int lg   = lane >> 4;        // k-octet (B) / C row group
    const int b0   = (blockIdx.x & 127) * NBC;
    const bool wr  = (blockIdx.x < 128);

    // h in B-fragment order: hf[lay][parity][kt][lane*8 + j] holds
    // h[k = 32*kt + 8*(lane>>4) + j][batch = lane&15].  k=50 = const 1.0.
    __shared__ __align__(16) _Float16 hf[NLAY][2][2][512];
    __shared__ float x_row[NBC][516];

    const float* Wih = (lay==0) ? Wih0 : WihL + (size_t)(lay-1)*G3*HDIM;
    const float* Whh = (lay==0) ? Whh0 : WhhL + (size_t)(lay-1)*G3*HDIM;
    const float* bih = (lay==0) ? bih0 : bihL + (lay-1)*G3;
    const float* bhh = (lay==0) ? bhh0 : bhhL + (lay-1)*G3;

    // ---- A fragments [gate][kt]; biases folded at k==50; scales folded ----
    const int  ur = 16*wt + lb;            // absolute gate-row 0..63
    const bool rv = ur < HDIM;
    f16x8 a_hh[3][2], a_ih[3][2];
#pragma unroll
    for (int g = 0; g < 3; ++g) {
        const int  gr  = 50*g + (rv ? ur : 0);
        const float scl = (g < 2) ? SCL_RZ : SCL_N;
#pragma unroll
        for (int kt = 0; kt < 2; ++kt) {
            f16x8 fh, fi;
#pragma unroll
            for (int j = 0; j < 8; ++j) {
                const int k = 32*kt + 8*lg + j;
                float vh = 0.f, vi = 0.f;
                if (rv) {
                    if (k < HDIM)       vh = Whh[gr*HDIM + k];
                    else if (k == HDIM) vh = bhh[gr];
                    if (lay == 0) {
                        if (kt == 0 && k == 0)      vi = Wih[gr];
                        else if (kt == 0 && k == 1) vi = bih[gr];
                    } else {
                        if (k < HDIM)       vi = Wih[gr*HDIM + k];
                        else if (k == HDIM) vi = bih[gr];
                    }
                }
                fh[j] = (_Float16)(vh * scl); fi[j] = (_Float16)(vi * scl);
            }
            a_hh[g][kt] = fh; a_ih[g][kt] = fi;
        }
    }

    // ---- stage x; init hf (zeros + bias 1.0 at k=50, both parities) ----
    for (int k = tid; k < NBC*TSEQ; k += 1024)
        x_row[k >> 9][k & 511] = xin[(size_t)(b0 + (k >> 9))*TSEQ + (k & 511)];
    for (int k = tid; k < NLAY*2*2*512; k += 1024) {
        const int w = k & 1023;     // within one lay/parity [2][512] block
        const bool isb = (w >= 770) && (w <= 890) && (((w - 770) & 7) == 0);
        ((_Float16*)hf)[k] = (_Float16)(isb ? 1.f : 0.f);
    }

    float hold[4];                     // persistent h for this wave's rows/lane
#pragma unroll
    for (int i = 0; i < 4; ++i) hold[i] = 0.f;
    __syncthreads();

    const int lane8 = lane * 8;
    f16x8 bh0 = *(const f16x8*)&hf[lay][1][0][lane8];
    f16x8 bh1 = *(const f16x8*)&hf[lay][1][1][lane8];
    f16x8 bx0{}, bx1{};
    if (lay == 0) {
#pragma unroll
        for (int j = 0; j < 8; ++j) bx0[j] = (_Float16)0.f;
        if (lg == 0) { bx0[0] = (_Float16)x_row[lb][0]; bx0[1] = (_Float16)1.f; }
    } else {
        bx0 = *(const f16x8*)&hf[lay-1][1][0][lane8];
        bx1 = *(const f16x8*)&hf[lay-1][1][1][lane8];
    }
    const f32x4 Z4 = {0.f, 0.f, 0.f, 0.f};
    const bool t3 = (wt == 3);   // tile 3: only rows 48,49 valid (lg==0, i<2)

    auto body = [&](int s, int P) {
        const int t = s - lay;
        if (t >= 0 && t < TSEQ) {
            f32x4 acc[3], accx;
#pragma unroll
            for (int g = 0; g < 3; ++g) acc[g] = MFMA(a_hh[g][0], bh0, Z4);
#pragma unroll
            for (int g = 0; g < 3; ++g) acc[g] = MFMA(a_hh[g][1], bh1, acc[g]);
#pragma unroll
            for (int g = 0; g < 2; ++g) acc[g] = MFMA(a_ih[g][0], bx0, acc[g]);
            accx = MFMA(a_ih[2][0], bx0, Z4);
            if (lay != 0) {
#pragma unroll
                for (int g = 0; g < 2; ++g) acc[g] = MFMA(a_ih[g][1], bx1, acc[g]);
                accx = MFMA(a_ih[2][1], bx1, accx);
            }

            // r,z sigmoids: rcp(1 + exp2(acc))
#pragma unroll
            for (int g = 0; g < 2; ++g)
#pragma unroll
                for (int i = 0; i < 4; ++i) {
                    if (t3 && i >= 2) continue;               // rows >= 50
                    acc[g][i] = rcpf(1.f + ex2(acc[g][i]));
                }

            // n gate + h update
            float hp[4];
#pragma unroll
            for (int i = 0; i < 4; ++i) {
                if (t3 && i >= 2) { hp[i] = 0.f; continue; }
                const float r  = acc[0][i];
                const float z  = acc[1][i];
                const float vp = accx[i] + r * acc[2][i];     // pre-scaled
                const float n  = 1.f - 2.f*rcpf(ex2(vp) + 1.f);
                const float h  = fmaf(z, hold[i] - n, n);     // (1-z)n + zh
                hold[i] = h;
                hp[i] = h;
            }

            // publish into fragment order: rows 16wt+4lg+{0..3} -> lane (lb+16*oct)
            {
                const int kt_w = wt >> 1;
                const int oct  = 2*(wt & 1) + (lg >> 1);
                const int j0   = 4*(lg & 1);
                _Float16* dst = &hf[lay][P][kt_w][(lb + 16*oct)*8 + j0];
                if (!t3) {
                    uint2 q; q.x = pk2(hp[0], hp[1]);
                             q.y = pk2(hp[2], hp[3]);
                    *(uint2*)dst = q;
                } else if (lg == 0) {   // rows 48,49; k=50 bias untouched
                    *(unsigned*)dst = pk2(hp[0], hp[1]);
                }
            }
        }
        __syncthreads();   // h(t) fully assembled in parity P

        bh0 = *(const f16x8*)&hf[lay][P][0][lane8];
        bh1 = *(const f16x8*)&hf[lay][P][1][lane8];
        if (lay == 0) {
            const int tt = (s+1 < TSEQ) ? s+1 : TSEQ-1;
            if (lg == 0) bx0[0] = (_Float16)x_row[lb][tt];
        } else {
            bx0 = *(const f16x8*)&hf[lay-1][P][0][lane8];
            bx1 = *(const f16x8*)&hf[lay-1][P][1][lane8];
        }
    };

    // 516 steps, unrolled x2 (parity compile-time); final body idles harmlessly
    for (int s = 0; s < TSEQ + NLAY; s += 2) {
        body(s,     0);
        body(s + 1, 1);
    }

    // ---- fused FC + sigmoid on layer-3 final h (t=511 -> s=514 -> parity 0) ----
    if (wr && tid < NBC) {
        float sacc = fcb[0];
#pragma unroll
        for (int j = 0; j < HDIM; ++j) {
            const int kt = j >> 5, oc = (j & 31) >> 3, jj = j & 7;
            sacc = fmaf((float)hf[NLAY-1][0][kt][(tid + 16*oc)*8 + jj], fcw[j], sacc);
        }
        out[b0 + tid] = rcpf(1.f + __expf(-sacc));
    }
}

extern "C" void kernel_launch(void* const* d_in, const int* in_sizes, int n_in,
                              void* d_out, int out_size, void* d_ws, size_t ws_size,
                              hipStream_t stream) {
    const float* x     = (const float*)d_in[0];
    const float* W_ih0 = (const float*)d_in[1];
    const float* W_hh0 = (const float*)d_in[2];
    const float* b_ih0 = (const float*)d_in[3];
    const float* b_hh0 = (const float*)d_in[4];
    const float* W_ih  = (const float*)d_in[5];
    const float* W_hh  = (const float*)d_in[6];
    const float* b_ih  = (const float*)d_in[7];
    const float* b_hh  = (const float*)d_in[8];
    const float* fc_w  = (const float*)d_in[9];
    const float* fc_b  = (const float*)d_in[10];
    float* out = (float*)d_out;

    dim3 grid(256), block(1024);   // blocks i and i+128 duplicate; i<128 writes
    gru_16wf<<<grid, block, 0, stream>>>(
        x, W_ih0, W_hh0, b_ih0, b_hh0,
        W_ih, W_hh, b_ih, b_hh, fc_w, fc_b, out);
}